// Round 12
// baseline (151.608 us; speedup 1.0000x reference)
//
#include <hip/hip_runtime.h>
#include <hip/hip_bf16.h>

// Problem constants
#define Bb 2
#define Nn 4096
#define Cc 1024
#define Hh 16
#define Dd 64
#define Mm (Bb*Nn)      // 8192
#define W2 10
#define WINSZ 21        // 2*W2+1

typedef __attribute__((ext_vector_type(8))) short  bf16x8s;
typedef __attribute__((ext_vector_type(4))) float  f32x4;
typedef __attribute__((ext_vector_type(4))) unsigned short us4;

#define AS1 __attribute__((address_space(1)))
#define AS3 __attribute__((address_space(3)))

__device__ __forceinline__ unsigned short f2bf(float f) {
  unsigned int u = __float_as_uint(f);
  u += 0x7FFFu + ((u >> 16) & 1u);
  return (unsigned short)(u >> 16);
}
__device__ __forceinline__ float bflo(unsigned int u) { return __uint_as_float(u << 16); }
__device__ __forceinline__ float bfhi(unsigned int u) { return __uint_as_float(u & 0xFFFF0000u); }

__device__ __forceinline__ us4 cvt4(float4 v) {
  us4 o;
  o.x = f2bf(v.x); o.y = f2bf(v.y); o.z = f2bf(v.z); o.w = f2bf(v.w);
  return o;
}

// ---------------- fused fp32->bf16 converts + bias gather (one launch) ----------------
__global__ __launch_bounds__(256) void cvt_all(const float4* __restrict__ q,
                                               const float4* __restrict__ wq,
                                               const float4* __restrict__ wk,
                                               const float4* __restrict__ wv,
                                               const float4* __restrict__ wo,
                                               const float* __restrict__ bq,
                                               const float* __restrict__ bk,
                                               const float* __restrict__ bv,
                                               us4* __restrict__ qb4,
                                               us4* __restrict__ wqkv4,
                                               us4* __restrict__ wo4,
                                               float* __restrict__ bqkv) {
  const int NQ = 2097152, NW = 262144, TOT = NQ + 4 * NW;
  const int gid = blockIdx.x * 256 + threadIdx.x;
  const int stride = gridDim.x * 256;
  for (int i = gid; i < TOT; i += stride) {
    if (i < NQ) {
      qb4[i] = cvt4(q[i]);
    } else {
      int j = i - NQ;
      int r = j >> 18, k = j & (NW - 1);
      if (r == 0)      wqkv4[k]          = cvt4(wq[k]);
      else if (r == 1) wqkv4[NW + k]     = cvt4(wk[k]);
      else if (r == 2) wqkv4[2 * NW + k] = cvt4(wv[k]);
      else             wo4[k]            = cvt4(wo[k]);
    }
  }
  if (gid < 3072) {
    float v = (gid < 1024) ? bq[gid] : (gid < 2048) ? bk[gid - 1024] : bv[gid - 2048];
    bqkv[gid] = v;
  }
}

// ---------------- 128x128 BK=32 flight-2 GEMM, 3 blocks/CU (K=1024) ----------------
// C[m,n] = sum_k A[m,k]*B[n,k] + bias[n]. 4 waves (2M x 2N, per-wave 64x64), BK=32,
// THREE 16KB LDS buffers (48KB -> 3 blocks/CU for cross-block stall overlap, m114).
// R7-proven ledger: STG(t+2) at tile-top; end-of-tile counted vmcnt(4) (t+1 landed,
// t+2 in flight) + ONE s_barrier. Swizzle: slot = chunk ^ (row&3) ^ ((row>>2)&3)
// (write side pre-swizzles the GLOBAL source; LDS dest stays linear per m104/m173).
template<bool OUT_BF16>
__global__ __launch_bounds__(256) void gemm_mb(const unsigned short* __restrict__ A,
                                               const unsigned short* __restrict__ Bm,
                                               const float* __restrict__ bias,
                                               void* __restrict__ Cout,
                                               int N) {
  constexpr int K = 1024, NT = 32;
  // per buffer: A[128][32] (4096 elems, 8KB) + B[128][32] = 8192 elems = 16 KB
  __shared__ unsigned short lds[3][8192];   // 48 KB

  const int tid = threadIdx.x, wid = tid >> 6, lane = tid & 63;
  const int wm = wid >> 1, wn = wid & 1;

  // bijective XCD swizzle + column-major tile walk (B panel dwells in L2/L3)
  const int nwg = gridDim.x, cpx = nwg >> 3, bid = blockIdx.x;
  const int swz = (bid & 7) * cpx + (bid >> 3);
  constexpr int NBM = Mm / 128;   // 64
  const int m0 = (swz % NBM) << 7, n0 = (swz / NBM) << 7;

  // staging: thread t covers row t>>2 (64 rows/instr per A-half), chunk-slot t&3.
  // Pre-swizzled global chunk g = (t&3) ^ (row&3) ^ ((row>>2)&3), row = t>>2.
  const int srow = tid >> 2;
  const int g = (tid & 3) ^ (srow & 3) ^ ((srow >> 2) & 3);
  const unsigned short* aS0 = A  + (size_t)(m0 + srow) * K + g * 8;
  const unsigned short* aS1 = aS0 + (size_t)64 * K;
  const unsigned short* bS0 = Bm + (size_t)(n0 + srow) * K + g * 8;
  const unsigned short* bS1 = bS0 + (size_t)64 * K;
  // LDS dests: linear, wave-uniform base + lane*16B
  const int d0 = wid * 512;   // elems; each instr covers 2048 elems (64 rows)

#define STG(bf, kt) do {                                                                    \
    const size_t ko = (size_t)(kt) * 32;                                                    \
    __builtin_amdgcn_global_load_lds((AS1 const void*)(aS0 + ko), (AS3 void*)(&lds[bf][       d0]), 16, 0, 0); \
    __builtin_amdgcn_global_load_lds((AS1 const void*)(aS1 + ko), (AS3 void*)(&lds[bf][2048 + d0]), 16, 0, 0); \
    __builtin_amdgcn_global_load_lds((AS1 const void*)(bS0 + ko), (AS3 void*)(&lds[bf][4096 + d0]), 16, 0, 0); \
    __builtin_amdgcn_global_load_lds((AS1 const void*)(bS1 + ko), (AS3 void*)(&lds[bf][6144 + d0]), 16, 0, 0); \
  } while (0)

  // fragment reads: row = w*64 + f*16 + (lane&15) -> row&3 = lane&3, (row>>2)&3 = (lane>>2)&3.
  // chunk = lane>>4; slot = chunk ^ (lane&3) ^ ((lane>>2)&3).
  const int slot8 = (((lane >> 4) ^ (lane & 3) ^ ((lane >> 2) & 3))) * 8;
  int aoff[4], boff[4];
#pragma unroll
  for (int f = 0; f < 4; ++f) {
    aoff[f] = (wm * 64 + f * 16 + (lane & 15)) * 32 + slot8;
    boff[f] = 4096 + (wn * 64 + f * 16 + (lane & 15)) * 32 + slot8;
  }

  f32x4 acc[4][4] = {};

  STG(0, 0);
  STG(1, 1);
  asm volatile("s_waitcnt vmcnt(4)" ::: "memory");   // tile-0's 4 loads landed
  __builtin_amdgcn_sched_barrier(0);
  __builtin_amdgcn_s_barrier();
  __builtin_amdgcn_sched_barrier(0);

  int cur = 0, stg = 2;
#pragma unroll 1
  for (int t = 0; t < NT; ++t) {
    if (t + 2 < NT) STG(stg, t + 2);   // buf[stg] freed at end-of-tile-(t-1) barrier

    const unsigned short* L = &lds[cur][0];
    bf16x8s a[4], b[4];
#pragma unroll
    for (int f = 0; f < 4; ++f) a[f] = *(const bf16x8s*)(L + aoff[f]);
#pragma unroll
    for (int f = 0; f < 4; ++f) b[f] = *(const bf16x8s*)(L + boff[f]);
    __builtin_amdgcn_s_setprio(1);
#pragma unroll
    for (int fm = 0; fm < 4; ++fm)
#pragma unroll
      for (int fn = 0; fn < 4; ++fn)
        acc[fm][fn] = __builtin_amdgcn_mfma_f32_16x16x32_bf16(a[fm], b[fn], acc[fm][fn], 0, 0, 0);
    __builtin_amdgcn_s_setprio(0);

    if (t + 1 < NT) {
      if (t + 2 < NT) asm volatile("s_waitcnt vmcnt(4)" ::: "memory");  // t+1 landed, t+2 in flight
      else            asm volatile("s_waitcnt vmcnt(0)" ::: "memory");  // tail
      __builtin_amdgcn_sched_barrier(0);
      __builtin_amdgcn_s_barrier();
      __builtin_amdgcn_sched_barrier(0);
    }
    cur = (cur == 2) ? 0 : cur + 1;
    stg = (stg == 2) ? 0 : stg + 1;
  }
#undef STG

  // epilogue: C/D layout col=lane&15, row=(lane>>4)*4+r
  const int r0 = m0 + wm * 64 + (lane >> 4) * 4;
  const int c0 = n0 + wn * 64 + (lane & 15);
#pragma unroll
  for (int fm = 0; fm < 4; ++fm) {
#pragma unroll
    for (int fn = 0; fn < 4; ++fn) {
      const int col = c0 + fn * 16;
      const float bv = bias[col];
#pragma unroll
      for (int r = 0; r < 4; ++r) {
        const int row = r0 + fm * 16 + r;
        const float v = acc[fm][fn][r] + bv;
        if (OUT_BF16)
          ((unsigned short*)Cout)[(size_t)row * N + col] = f2bf(v);
        else
          ((float*)Cout)[(size_t)row * N + col] = v;
      }
    }
  }
}

// ---------------- banded local attention: 2 threads per (b,h,n) row ----------------
#define TN 128
#define KVROWS (TN + 2 * W2)   // 148 staged rows

__global__ void attn_kernel(const unsigned short* __restrict__ QKV, // [Mm][3072]
                            unsigned short* __restrict__ AO,        // [Mm][1024]
                            float* __restrict__ attn_last) {        // [Bb*Hh*11]
  __shared__ uint4 Kl[KVROWS * 8];
  __shared__ uint4 Vl[KVROWS * 8];

  const int nt = Nn / TN;            // 32
  const int bid = blockIdx.x;
  const int tile = bid & (nt - 1);
  const int bh = bid / nt;
  const int h = bh & (Hh - 1), b = bh / Hh;
  const int n0 = tile * TN;
  const int tid = threadIdx.x;

  for (int idx = tid; idx < KVROWS * 8; idx += 256) {
    const int r = idx >> 3, c = idx & 7;
    const int pos = n0 - W2 + r;
    uint4 kv = make_uint4(0, 0, 0, 0), vv = make_uint4(0, 0, 0, 0);
    if (pos >= 0 && pos < Nn) {
      const uint4* row = (const uint4*)(QKV + (size_t)(b * Nn + pos) * 3072);
      kv = row[128 + h * 8 + c];
      vv = row[256 + h * 8 + c];
    }
    const int slot = c ^ (r & 7);
    Kl[r * 8 + slot] = kv;
    Vl[r * 8 + slot] = vv;
  }
  __syncthreads();

  const int row  = tid >> 1;
  const int half = tid & 1;
  const int n = n0 + row;
  const size_t m = (size_t)b * Nn + n;

  const uint4* qrow = (const uint4*)(QKV + m * 3072) + h * 8 + half * 4;
  const uint4 qd0 = qrow[0], qd1 = qrow[1], qd2 = qrow[2], qd3 = qrow[3];

  float p[WINSZ];
#pragma unroll
  for (int w = 0; w < WINSZ; ++w) p[w] = 0.f;

#pragma unroll
  for (int c = 0; c < 4; ++c) {
    const uint4 qv = (c == 0) ? qd0 : (c == 1) ? qd1 : (c == 2) ? qd2 : qd3;
    const float q0 = bflo(qv.x), q1 = bfhi(qv.x);
    const float q2 = bflo(qv.y), q3 = bfhi(qv.y);
    const float q4 = bflo(qv.z), q5 = bfhi(qv.z);
    const float q6 = bflo(qv.w), q7 = bfhi(qv.w);
#pragma unroll 7
    for (int w = 0; w < WINSZ; ++w) {
      const int r = row + w;
      const uint4 v = Kl[r * 8 + ((half * 4 + c) ^ (r & 7))];
      float a0 = q0 * bflo(v.x);
      float a1 = q1 * bfhi(v.x);
      a0 += q2 * bflo(v.y);
      a1 += q3 * bfhi(v.y);
      a0 += q4 * bflo(v.z);
      a1 += q5 * bfhi(v.z);
      a0 += q6 * bflo(v.w);
      a1 += q7 * bfhi(v.w);
      p[w] += a0 + a1;
    }
  }

#pragma unroll
  for (int w = 0; w < WINSZ; ++w) {
    float t = p[w];
    t += __shfl_xor(t, 1, 64);
    const int pos = n - W2 + w;
    p[w] = (pos < 0 || pos >= Nn) ? -1e30f : t * 0.125f;
  }
  float mx = p[0];
#pragma unroll
  for (int w = 1; w < WINSZ; ++w) mx = fmaxf(mx, p[w]);
  float sum = 0.f;
#pragma unroll
  for (int w = 0; w < WINSZ; ++w) { p[w] = __expf(p[w] - mx); sum += p[w]; }
  const float inv = 1.0f / sum;

  if (n == Nn - 1 && half == 0) {
#pragma unroll
    for (int w = 0; w <= W2; ++w)
      attn_last[(b * Hh + h) * (W2 + 1) + w] = p[w] * inv;
  }

  uint4* orow = (uint4*)(AO + m * Cc + h * Dd) + half * 4;
#pragma unroll
  for (int c = 0; c < 4; ++c) {
    float o0 = 0.f, o1 = 0.f, o2 = 0.f, o3 = 0.f;
    float o4 = 0.f, o5 = 0.f, o6 = 0.f, o7 = 0.f;
#pragma unroll 7
    for (int w = 0; w < WINSZ; ++w) {
      const int r = row + w;
      const uint4 v = Vl[r * 8 + ((half * 4 + c) ^ (r & 7))];
      const float pw = p[w];
      o0 += pw * bflo(v.x);
      o1 += pw * bfhi(v.x);
      o2 += pw * bflo(v.y);
      o3 += pw * bfhi(v.y);
      o4 += pw * bflo(v.z);
      o5 += pw * bfhi(v.z);
      o6 += pw * bflo(v.w);
      o7 += pw * bfhi(v.w);
    }
    unsigned int d0 = (unsigned int)f2bf(o0 * inv) | ((unsigned int)f2bf(o1 * inv) << 16);
    unsigned int d1 = (unsigned int)f2bf(o2 * inv) | ((unsigned int)f2bf(o3 * inv) << 16);
    unsigned int d2 = (unsigned int)f2bf(o4 * inv) | ((unsigned int)f2bf(o5 * inv) << 16);
    unsigned int d3 = (unsigned int)f2bf(o6 * inv) | ((unsigned int)f2bf(o7 * inv) << 16);
    orow[c] = make_uint4(d0, d1, d2, d3);
  }
}

// ---------------- launch ----------------
extern "C" void kernel_launch(void* const* d_in, const int* in_sizes, int n_in,
                              void* d_out, int out_size, void* d_ws, size_t ws_size,
                              hipStream_t stream) {
  const float* q    = (const float*)d_in[0];
  const float* Wq_w = (const float*)d_in[1];
  const float* Wq_b = (const float*)d_in[2];
  const float* Wk_w = (const float*)d_in[3];
  const float* Wk_b = (const float*)d_in[4];
  const float* Wv_w = (const float*)d_in[5];
  const float* Wv_b = (const float*)d_in[6];
  const float* Wo_w = (const float*)d_in[7];
  const float* Wo_b = (const float*)d_in[8];
  float* out = (float*)d_out;                       // [Mm*Cc] + [Bb*Hh*11]
  float* attn_last = out + (size_t)Mm * Cc;

  // workspace carve (bytes)
  char* ws = (char*)d_ws;
  unsigned short* qb   = (unsigned short*)(ws);                       // 16 MB
  unsigned short* Wqkv = (unsigned short*)(ws + 16777216);            // 6 MB
  unsigned short* Wo16 = (unsigned short*)(ws + 16777216 + 6291456);  // 2 MB
  float*          bqkv = (float*)(ws + 25165824);                     // 3072 f32
  unsigned short* QKV  = (unsigned short*)(ws + 25182208);            // 48 MB
  unsigned short* AO   = (unsigned short*)(ws + 75513856);            // 16 MB

  // 1) fused converts (q, Wq, Wk, Wv, Wo) + bias gather — one launch
  cvt_all<<<2048, 256, 0, stream>>>((const float4*)q,
                                    (const float4*)Wq_w, (const float4*)Wk_w,
                                    (const float4*)Wv_w, (const float4*)Wo_w,
                                    Wq_b, Wk_b, Wv_b,
                                    (us4*)qb, (us4*)Wqkv, (us4*)Wo16, bqkv);

  // 2) fused QKV projection: [8192,1024] x [3072,1024]^T -> bf16 [8192,3072]
  {
    dim3 grid((Mm / 128) * (3072 / 128));   // 64*24 = 1536, %8==0
    gemm_mb<true><<<grid, 256, 0, stream>>>(qb, Wqkv, bqkv, (void*)QKV, 3072);
  }

  // 3) windowed attention -> bf16 [8192,1024] + attn_last tail of d_out
  {
    dim3 grid(Bb * Hh * (Nn / TN));
    attn_kernel<<<grid, 256, 0, stream>>>(QKV, AO, attn_last);
  }

  // 4) output projection: [8192,1024] x [1024,1024]^T -> fp32 d_out
  {
    dim3 grid((Mm / 128) * (Cc / 128));     // 64*8 = 512, %8==0
    gemm_mb<false><<<grid, 256, 0, stream>>>(AO, Wo16, Wo_b, (void*)out, Cc);
  }
}

// Round 13
// 141.103 us; speedup vs baseline: 1.0744x; 1.0744x over previous
//
#include <hip/hip_runtime.h>
#include <hip/hip_bf16.h>

// Problem constants
#define Bb 2
#define Nn 4096
#define Cc 1024
#define Hh 16
#define Dd 64
#define Mm (Bb*Nn)      // 8192
#define W2 10
#define WINSZ 21        // 2*W2+1

typedef __attribute__((ext_vector_type(8))) short  bf16x8s;
typedef __attribute__((ext_vector_type(4))) float  f32x4;
typedef __attribute__((ext_vector_type(4))) unsigned short us4;

#define AS1 __attribute__((address_space(1)))
#define AS3 __attribute__((address_space(3)))

__device__ __forceinline__ unsigned short f2bf(float f) {
  unsigned int u = __float_as_uint(f);
  u += 0x7FFFu + ((u >> 16) & 1u);
  return (unsigned short)(u >> 16);
}
__device__ __forceinline__ float bflo(unsigned int u) { return __uint_as_float(u << 16); }
__device__ __forceinline__ float bfhi(unsigned int u) { return __uint_as_float(u & 0xFFFF0000u); }

__device__ __forceinline__ us4 cvt4(float4 v) {
  us4 o;
  o.x = f2bf(v.x); o.y = f2bf(v.y); o.z = f2bf(v.z); o.w = f2bf(v.w);
  return o;
}

// ---------------- fused fp32->bf16 converts + bias gather (one launch) ----------------
__global__ __launch_bounds__(256) void cvt_all(const float4* __restrict__ q,
                                               const float4* __restrict__ wq,
                                               const float4* __restrict__ wk,
                                               const float4* __restrict__ wv,
                                               const float4* __restrict__ wo,
                                               const float* __restrict__ bq,
                                               const float* __restrict__ bk,
                                               const float* __restrict__ bv,
                                               us4* __restrict__ qb4,
                                               us4* __restrict__ wqkv4,
                                               us4* __restrict__ wo4,
                                               float* __restrict__ bqkv) {
  const int NQ = 2097152, NW = 262144, TOT = NQ + 4 * NW;
  const int gid = blockIdx.x * 256 + threadIdx.x;
  const int stride = gridDim.x * 256;
  for (int i = gid; i < TOT; i += stride) {
    if (i < NQ) {
      qb4[i] = cvt4(q[i]);
    } else {
      int j = i - NQ;
      int r = j >> 18, k = j & (NW - 1);
      if (r == 0)      wqkv4[k]          = cvt4(wq[k]);
      else if (r == 1) wqkv4[NW + k]     = cvt4(wk[k]);
      else if (r == 2) wqkv4[2 * NW + k] = cvt4(wv[k]);
      else             wo4[k]            = cvt4(wo[k]);
    }
  }
  if (gid < 3072) {
    float v = (gid < 1024) ? bq[gid] : (gid < 2048) ? bk[gid - 1024] : bv[gid - 2048];
    bqkv[gid] = v;
  }
}

// ---------------- 256x256 BK=32 flight-2 GEMM (K=1024) — QKV projection ----------------
// 8 waves (2M x 4N, per-wave 128x64). THREE 32KB buffers (96KB). R7-proven ledger:
// STG(t+2) at tile-top; end-of-tile counted vmcnt(4) (t+1 landed, t+2 in flight) +
// ONE s_barrier. BK=32 swizzle: slot = chunk ^ ((row>>1)&3); write side pre-swizzles
// the GLOBAL chunk g = (l&3)^((l>>3)&3); LDS dest linear (m104/m173).
template<bool OUT_BF16>
__global__ __launch_bounds__(512) void gemm_b256(const unsigned short* __restrict__ A,
                                                 const unsigned short* __restrict__ Bm,
                                                 const float* __restrict__ bias,
                                                 void* __restrict__ Cout,
                                                 int N) {
  constexpr int K = 1024, NT = 32;
  // per buffer: A[256][32] (8192 elems, 16KB) + B[256][32] = 16384 elems = 32 KB
  __shared__ unsigned short lds[3][16384];   // 96 KB

  const int tid = threadIdx.x, wid = tid >> 6, lane = tid & 63;
  const int wm = wid >> 2, wn = wid & 3;

  // bijective XCD swizzle + column-major tile walk
  const int nwg = gridDim.x, cpx = nwg >> 3, bid = blockIdx.x;
  const int swz = (bid & 7) * cpx + (bid >> 3);
  constexpr int NBM = Mm / 256;   // 32
  const int m0 = (swz % NBM) << 8, n0 = (swz / NBM) << 8;

  // staging: wave w covers rows 32w..32w+31 of A and of B (2 instrs each, 16 rows/instr).
  // lane l -> row base + (l>>2), slot l&3; pre-swizzled global chunk g = (l&3)^((l>>3)&3).
  const int srow = lane >> 2;
  const int g8 = ((lane & 3) ^ ((lane >> 3) & 3)) * 8;
  const unsigned short* aS0 = A  + (size_t)(m0 + wid * 32 + srow) * K + g8;
  const unsigned short* aS1 = aS0 + (size_t)16 * K;
  const unsigned short* bS0 = Bm + (size_t)(n0 + wid * 32 + srow) * K + g8;
  const unsigned short* bS1 = bS0 + (size_t)16 * K;
  const int dA0 = wid * 1024, dA1 = wid * 1024 + 512;          // elems
  const int dB0 = 8192 + wid * 1024, dB1 = 8192 + wid * 1024 + 512;

#define STG(bf, kt) do {                                                                    \
    const size_t ko = (size_t)(kt) * 32;                                                    \
    __builtin_amdgcn_global_load_lds((AS1 const void*)(aS0 + ko), (AS3 void*)(&lds[bf][dA0]), 16, 0, 0); \
    __builtin_amdgcn_global_load_lds((AS1 const void*)(aS1 + ko), (AS3 void*)(&lds[bf][dA1]), 16, 0, 0); \
    __builtin_amdgcn_global_load_lds((AS1 const void*)(bS0 + ko), (AS3 void*)(&lds[bf][dB0]), 16, 0, 0); \
    __builtin_amdgcn_global_load_lds((AS1 const void*)(bS1 + ko), (AS3 void*)(&lds[bf][dB1]), 16, 0, 0); \
  } while (0)

  // fragment reads: row = base + f*16 + (lane&15); (row>>1)&3 = ((lane&15)>>1)&3.
  // chunk = lane>>4 (k = chunk*8); slot = chunk ^ ((row>>1)&3).
  const int slot8 = ((lane >> 4) ^ (((lane & 15) >> 1) & 3)) * 8;
  int aoff[8], boff[4];
#pragma unroll
  for (int f = 0; f < 8; ++f)
    aoff[f] = (wm * 128 + f * 16 + (lane & 15)) * 32 + slot8;
#pragma unroll
  for (int f = 0; f < 4; ++f)
    boff[f] = 8192 + (wn * 64 + f * 16 + (lane & 15)) * 32 + slot8;

  f32x4 acc[8][4] = {};

  STG(0, 0);
  STG(1, 1);
  asm volatile("s_waitcnt vmcnt(4)" ::: "memory");   // tile-0's 4 loads landed
  __builtin_amdgcn_sched_barrier(0);
  __builtin_amdgcn_s_barrier();
  __builtin_amdgcn_sched_barrier(0);

  int cur = 0, stg = 2;
#pragma unroll 1
  for (int t = 0; t < NT; ++t) {
    if (t + 2 < NT) STG(stg, t + 2);   // buf[stg] freed at end-of-tile-(t-1) barrier

    const unsigned short* L = &lds[cur][0];
    bf16x8s a[8], b[4];
#pragma unroll
    for (int f = 0; f < 8; ++f) a[f] = *(const bf16x8s*)(L + aoff[f]);
#pragma unroll
    for (int f = 0; f < 4; ++f) b[f] = *(const bf16x8s*)(L + boff[f]);
    __builtin_amdgcn_s_setprio(1);
#pragma unroll
    for (int fm = 0; fm < 8; ++fm)
#pragma unroll
      for (int fn = 0; fn < 4; ++fn)
        acc[fm][fn] = __builtin_amdgcn_mfma_f32_16x16x32_bf16(a[fm], b[fn], acc[fm][fn], 0, 0, 0);
    __builtin_amdgcn_s_setprio(0);

    if (t + 1 < NT) {
      if (t + 2 < NT) asm volatile("s_waitcnt vmcnt(4)" ::: "memory");  // t+1 landed, t+2 in flight
      else            asm volatile("s_waitcnt vmcnt(0)" ::: "memory");  // tail
      __builtin_amdgcn_sched_barrier(0);
      __builtin_amdgcn_s_barrier();
      __builtin_amdgcn_sched_barrier(0);
    }
    cur = (cur == 2) ? 0 : cur + 1;
    stg = (stg == 2) ? 0 : stg + 1;
  }
#undef STG

  // epilogue: C/D layout col=lane&15, row=(lane>>4)*4+r
  const int r0 = m0 + wm * 128 + (lane >> 4) * 4;
  const int c0 = n0 + wn * 64 + (lane & 15);
#pragma unroll
  for (int fm = 0; fm < 8; ++fm) {
#pragma unroll
    for (int fn = 0; fn < 4; ++fn) {
      const int col = c0 + fn * 16;
      const float bv = bias[col];
#pragma unroll
      for (int r = 0; r < 4; ++r) {
        const int row = r0 + fm * 16 + r;
        const float v = acc[fm][fn][r] + bv;
        if (OUT_BF16)
          ((unsigned short*)Cout)[(size_t)row * N + col] = f2bf(v);
        else
          ((float*)Cout)[(size_t)row * N + col] = v;
      }
    }
  }
}

// ---------------- 128x256 flight-2 GEMM (R7-proven) — output projection ----------------
template<bool OUT_BF16>
__global__ __launch_bounds__(512) void gemm_p3(const unsigned short* __restrict__ A,
                                               const unsigned short* __restrict__ Bm,
                                               const float* __restrict__ bias,
                                               void* __restrict__ Cout,
                                               int N) {
  constexpr int K = 1024, NT = 16;
  __shared__ unsigned short lds[3][24576];   // 144 KB

  const int tid = threadIdx.x, wid = tid >> 6, lane = tid & 63;
  const int wm = wid >> 2, wn = wid & 3;

  const int nwg = gridDim.x, cpx = nwg >> 3, bid = blockIdx.x;
  const int swz = (bid & 7) * cpx + (bid >> 3);
  constexpr int NBM = Mm / 128;   // 64
  const int m0 = (swz % NBM) << 7, n0 = (swz / NBM) << 8;

  const int rbase = wid * 8 + (lane >> 3);
  const int cst = ((lane & 7) ^ (lane >> 3)) * 8;
  const unsigned short* aS0 = A + (size_t)(m0 + rbase) * K + cst;
  const unsigned short* aS1 = A + (size_t)(m0 + 64 + rbase) * K + cst;
  const unsigned short* bS0 = Bm + (size_t)(n0 + rbase) * K + cst;
  const unsigned short* bS1 = Bm + (size_t)(n0 + 64 + rbase) * K + cst;
  const unsigned short* bS2 = Bm + (size_t)(n0 + 128 + rbase) * K + cst;
  const unsigned short* bS3 = Bm + (size_t)(n0 + 192 + rbase) * K + cst;
  const int dA0 = wid * 512, dA1 = 4096 + wid * 512;
  const int dB0 = 8192 + wid * 512, dB1 = 12288 + wid * 512;
  const int dB2 = 16384 + wid * 512, dB3 = 20480 + wid * 512;

#define STG(bf, kt) do {                                                                   \
    const size_t ko = (size_t)(kt) * 64;                                                   \
    __builtin_amdgcn_global_load_lds((AS1 const void*)(aS0 + ko), (AS3 void*)(&lds[bf][dA0]), 16, 0, 0); \
    __builtin_amdgcn_global_load_lds((AS1 const void*)(aS1 + ko), (AS3 void*)(&lds[bf][dA1]), 16, 0, 0); \
    __builtin_amdgcn_global_load_lds((AS1 const void*)(bS0 + ko), (AS3 void*)(&lds[bf][dB0]), 16, 0, 0); \
    __builtin_amdgcn_global_load_lds((AS1 const void*)(bS1 + ko), (AS3 void*)(&lds[bf][dB1]), 16, 0, 0); \
    __builtin_amdgcn_global_load_lds((AS1 const void*)(bS2 + ko), (AS3 void*)(&lds[bf][dB2]), 16, 0, 0); \
    __builtin_amdgcn_global_load_lds((AS1 const void*)(bS3 + ko), (AS3 void*)(&lds[bf][dB3]), 16, 0, 0); \
  } while (0)

  int aoff[2][4], boff[2][4];
#pragma unroll
  for (int kk = 0; kk < 2; ++kk) {
    const int chs = ((kk * 4 + (lane >> 4)) ^ (lane & 7)) * 8;
#pragma unroll
    for (int f = 0; f < 4; ++f) {
      aoff[kk][f] = (wm * 64 + f * 16 + (lane & 15)) * 64 + chs;
      boff[kk][f] = 8192 + (wn * 64 + f * 16 + (lane & 15)) * 64 + chs;
    }
  }

  f32x4 acc[4][4] = {};

  STG(0, 0);
  STG(1, 1);
  asm volatile("s_waitcnt vmcnt(6)" ::: "memory");
  __builtin_amdgcn_sched_barrier(0);
  __builtin_amdgcn_s_barrier();
  __builtin_amdgcn_sched_barrier(0);

  int cur = 0, stg = 2;
  for (int t = 0; t < NT; ++t) {
    if (t + 2 < NT) STG(stg, t + 2);

    const unsigned short* L = &lds[cur][0];
    bf16x8s a[2][4], b[2][4];
#pragma unroll
    for (int kk = 0; kk < 2; ++kk) {
#pragma unroll
      for (int f = 0; f < 4; ++f) {
        a[kk][f] = *(const bf16x8s*)(L + aoff[kk][f]);
        b[kk][f] = *(const bf16x8s*)(L + boff[kk][f]);
      }
    }
    __builtin_amdgcn_s_setprio(1);
#pragma unroll
    for (int kk = 0; kk < 2; ++kk)
#pragma unroll
      for (int fm = 0; fm < 4; ++fm)
#pragma unroll
        for (int fn = 0; fn < 4; ++fn)
          acc[fm][fn] = __builtin_amdgcn_mfma_f32_16x16x32_bf16(a[kk][fm], b[kk][fn], acc[fm][fn], 0, 0, 0);
    __builtin_amdgcn_s_setprio(0);

    if (t + 1 < NT) {
      if (t + 2 < NT) asm volatile("s_waitcnt vmcnt(6)" ::: "memory");
      else            asm volatile("s_waitcnt vmcnt(0)" ::: "memory");
      __builtin_amdgcn_sched_barrier(0);
      __builtin_amdgcn_s_barrier();
      __builtin_amdgcn_sched_barrier(0);
    }
    cur = (cur == 2) ? 0 : cur + 1;
    stg = (stg == 2) ? 0 : stg + 1;
  }
#undef STG

  const int r0 = m0 + wm * 64 + (lane >> 4) * 4;
  const int c0 = n0 + wn * 64 + (lane & 15);
#pragma unroll
  for (int fm = 0; fm < 4; ++fm) {
#pragma unroll
    for (int fn = 0; fn < 4; ++fn) {
      const int col = c0 + fn * 16;
      const float bv = bias[col];
#pragma unroll
      for (int r = 0; r < 4; ++r) {
        const int row = r0 + fm * 16 + r;
        const float v = acc[fm][fn][r] + bv;
        if (OUT_BF16)
          ((unsigned short*)Cout)[(size_t)row * N + col] = f2bf(v);
        else
          ((float*)Cout)[(size_t)row * N + col] = v;
      }
    }
  }
}

// ---------------- banded local attention: 2 threads per (b,h,n) row ----------------
#define TN 128
#define KVROWS (TN + 2 * W2)   // 148 staged rows

__global__ void attn_kernel(const unsigned short* __restrict__ QKV, // [Mm][3072]
                            unsigned short* __restrict__ AO,        // [Mm][1024]
                            float* __restrict__ attn_last) {        // [Bb*Hh*11]
  __shared__ uint4 Kl[KVROWS * 8];
  __shared__ uint4 Vl[KVROWS * 8];

  const int nt = Nn / TN;            // 32
  const int bid = blockIdx.x;
  const int tile = bid & (nt - 1);
  const int bh = bid / nt;
  const int h = bh & (Hh - 1), b = bh / Hh;
  const int n0 = tile * TN;
  const int tid = threadIdx.x;

  for (int idx = tid; idx < KVROWS * 8; idx += 256) {
    const int r = idx >> 3, c = idx & 7;
    const int pos = n0 - W2 + r;
    uint4 kv = make_uint4(0, 0, 0, 0), vv = make_uint4(0, 0, 0, 0);
    if (pos >= 0 && pos < Nn) {
      const uint4* row = (const uint4*)(QKV + (size_t)(b * Nn + pos) * 3072);
      kv = row[128 + h * 8 + c];
      vv = row[256 + h * 8 + c];
    }
    const int slot = c ^ (r & 7);
    Kl[r * 8 + slot] = kv;
    Vl[r * 8 + slot] = vv;
  }
  __syncthreads();

  const int row  = tid >> 1;
  const int half = tid & 1;
  const int n = n0 + row;
  const size_t m = (size_t)b * Nn + n;

  const uint4* qrow = (const uint4*)(QKV + m * 3072) + h * 8 + half * 4;
  const uint4 qd0 = qrow[0], qd1 = qrow[1], qd2 = qrow[2], qd3 = qrow[3];

  float p[WINSZ];
#pragma unroll
  for (int w = 0; w < WINSZ; ++w) p[w] = 0.f;

#pragma unroll
  for (int c = 0; c < 4; ++c) {
    const uint4 qv = (c == 0) ? qd0 : (c == 1) ? qd1 : (c == 2) ? qd2 : qd3;
    const float q0 = bflo(qv.x), q1 = bfhi(qv.x);
    const float q2 = bflo(qv.y), q3 = bfhi(qv.y);
    const float q4 = bflo(qv.z), q5 = bfhi(qv.z);
    const float q6 = bflo(qv.w), q7 = bfhi(qv.w);
#pragma unroll 7
    for (int w = 0; w < WINSZ; ++w) {
      const int r = row + w;
      const uint4 v = Kl[r * 8 + ((half * 4 + c) ^ (r & 7))];
      float a0 = q0 * bflo(v.x);
      float a1 = q1 * bfhi(v.x);
      a0 += q2 * bflo(v.y);
      a1 += q3 * bfhi(v.y);
      a0 += q4 * bflo(v.z);
      a1 += q5 * bfhi(v.z);
      a0 += q6 * bflo(v.w);
      a1 += q7 * bfhi(v.w);
      p[w] += a0 + a1;
    }
  }

#pragma unroll
  for (int w = 0; w < WINSZ; ++w) {
    float t = p[w];
    t += __shfl_xor(t, 1, 64);
    const int pos = n - W2 + w;
    p[w] = (pos < 0 || pos >= Nn) ? -1e30f : t * 0.125f;
  }
  float mx = p[0];
#pragma unroll
  for (int w = 1; w < WINSZ; ++w) mx = fmaxf(mx, p[w]);
  float sum = 0.f;
#pragma unroll
  for (int w = 0; w < WINSZ; ++w) { p[w] = __expf(p[w] - mx); sum += p[w]; }
  const float inv = 1.0f / sum;

  if (n == Nn - 1 && half == 0) {
#pragma unroll
    for (int w = 0; w <= W2; ++w)
      attn_last[(b * Hh + h) * (W2 + 1) + w] = p[w] * inv;
  }

  uint4* orow = (uint4*)(AO + m * Cc + h * Dd) + half * 4;
#pragma unroll
  for (int c = 0; c < 4; ++c) {
    float o0 = 0.f, o1 = 0.f, o2 = 0.f, o3 = 0.f;
    float o4 = 0.f, o5 = 0.f, o6 = 0.f, o7 = 0.f;
#pragma unroll 7
    for (int w = 0; w < WINSZ; ++w) {
      const int r = row + w;
      const uint4 v = Vl[r * 8 + ((half * 4 + c) ^ (r & 7))];
      const float pw = p[w];
      o0 += pw * bflo(v.x);
      o1 += pw * bfhi(v.x);
      o2 += pw * bflo(v.y);
      o3 += pw * bfhi(v.y);
      o4 += pw * bflo(v.z);
      o5 += pw * bfhi(v.z);
      o6 += pw * bflo(v.w);
      o7 += pw * bfhi(v.w);
    }
    unsigned int d0 = (unsigned int)f2bf(o0 * inv) | ((unsigned int)f2bf(o1 * inv) << 16);
    unsigned int d1 = (unsigned int)f2bf(o2 * inv) | ((unsigned int)f2bf(o3 * inv) << 16);
    unsigned int d2 = (unsigned int)f2bf(o4 * inv) | ((unsigned int)f2bf(o5 * inv) << 16);
    unsigned int d3 = (unsigned int)f2bf(o6 * inv) | ((unsigned int)f2bf(o7 * inv) << 16);
    orow[c] = make_uint4(d0, d1, d2, d3);
  }
}

// ---------------- launch ----------------
extern "C" void kernel_launch(void* const* d_in, const int* in_sizes, int n_in,
                              void* d_out, int out_size, void* d_ws, size_t ws_size,
                              hipStream_t stream) {
  const float* q    = (const float*)d_in[0];
  const float* Wq_w = (const float*)d_in[1];
  const float* Wq_b = (const float*)d_in[2];
  const float* Wk_w = (const float*)d_in[3];
  const float* Wk_b = (const float*)d_in[4];
  const float* Wv_w = (const float*)d_in[5];
  const float* Wv_b = (const float*)d_in[6];
  const float* Wo_w = (const float*)d_in[7];
  const float* Wo_b = (const float*)d_in[8];
  float* out = (float*)d_out;                       // [Mm*Cc] + [Bb*Hh*11]
  float* attn_last = out + (size_t)Mm * Cc;

  // workspace carve (bytes)
  char* ws = (char*)d_ws;
  unsigned short* qb   = (unsigned short*)(ws);                       // 16 MB
  unsigned short* Wqkv = (unsigned short*)(ws + 16777216);            // 6 MB
  unsigned short* Wo16 = (unsigned short*)(ws + 16777216 + 6291456);  // 2 MB
  float*          bqkv = (float*)(ws + 25165824);                     // 3072 f32
  unsigned short* QKV  = (unsigned short*)(ws + 25182208);            // 48 MB
  unsigned short* AO   = (unsigned short*)(ws + 75513856);            // 16 MB

  // 1) fused converts (q, Wq, Wk, Wv, Wo) + bias gather — one launch
  cvt_all<<<2048, 256, 0, stream>>>((const float4*)q,
                                    (const float4*)Wq_w, (const float4*)Wk_w,
                                    (const float4*)Wv_w, (const float4*)Wo_w,
                                    Wq_b, Wk_b, Wv_b,
                                    (us4*)qb, (us4*)Wqkv, (us4*)Wo16, bqkv);

  // 2) fused QKV projection: [8192,1024] x [3072,1024]^T -> bf16 [8192,3072]
  {
    dim3 grid((Mm / 256) * (3072 / 256));   // 32*12 = 384, %8==0
    gemm_b256<true><<<grid, 512, 0, stream>>>(qb, Wqkv, bqkv, (void*)QKV, 3072);
  }

  // 3) windowed attention -> bf16 [8192,1024] + attn_last tail of d_out
  {
    dim3 grid(Bb * Hh * (Nn / TN));
    attn_kernel<<<grid, 256, 0, stream>>>(QKV, AO, attn_last);
  }

  // 4) output projection: [8192,1024] x [1024,1024]^T -> fp32 d_out
  {
    dim3 grid((Mm / 128) * (Cc / 256));     // 256, %8==0
    gemm_p3<false><<<grid, 512, 0, stream>>>(AO, Wo16, Wo_b, (void*)out, Cc);
  }
}

// Round 14
// 137.535 us; speedup vs baseline: 1.1023x; 1.0259x over previous
//
#include <hip/hip_runtime.h>
#include <hip/hip_bf16.h>

// Problem constants
#define Bb 2
#define Nn 4096
#define Cc 1024
#define Hh 16
#define Dd 64
#define Mm (Bb*Nn)      // 8192
#define W2 10
#define WINSZ 21        // 2*W2+1

typedef __attribute__((ext_vector_type(8))) short  bf16x8s;
typedef __attribute__((ext_vector_type(4))) float  f32x4;
typedef __attribute__((ext_vector_type(4))) unsigned short us4;

#define AS1 __attribute__((address_space(1)))
#define AS3 __attribute__((address_space(3)))

__device__ __forceinline__ unsigned short f2bf(float f) {
  unsigned int u = __float_as_uint(f);
  u += 0x7FFFu + ((u >> 16) & 1u);
  return (unsigned short)(u >> 16);
}
__device__ __forceinline__ float bflo(unsigned int u) { return __uint_as_float(u << 16); }
__device__ __forceinline__ float bfhi(unsigned int u) { return __uint_as_float(u & 0xFFFF0000u); }

__device__ __forceinline__ us4 cvt4(float4 v) {
  us4 o;
  o.x = f2bf(v.x); o.y = f2bf(v.y); o.z = f2bf(v.z); o.w = f2bf(v.w);
  return o;
}

// ---------------- fused fp32->bf16 converts + bias gather (one launch) ----------------
__global__ __launch_bounds__(256) void cvt_all(const float4* __restrict__ q,
                                               const float4* __restrict__ wq,
                                               const float4* __restrict__ wk,
                                               const float4* __restrict__ wv,
                                               const float4* __restrict__ wo,
                                               const float* __restrict__ bq,
                                               const float* __restrict__ bk,
                                               const float* __restrict__ bv,
                                               us4* __restrict__ qb4,
                                               us4* __restrict__ wqkv4,
                                               us4* __restrict__ wo4,
                                               float* __restrict__ bqkv) {
  const int NQ = 2097152, NW = 262144, TOT = NQ + 4 * NW;
  const int gid = blockIdx.x * 256 + threadIdx.x;
  const int stride = gridDim.x * 256;
  for (int i = gid; i < TOT; i += stride) {
    if (i < NQ) {
      qb4[i] = cvt4(q[i]);
    } else {
      int j = i - NQ;
      int r = j >> 18, k = j & (NW - 1);
      if (r == 0)      wqkv4[k]          = cvt4(wq[k]);
      else if (r == 1) wqkv4[NW + k]     = cvt4(wk[k]);
      else if (r == 2) wqkv4[2 * NW + k] = cvt4(wv[k]);
      else             wo4[k]            = cvt4(wo[k]);
    }
  }
  if (gid < 3072) {
    float v = (gid < 1024) ? bq[gid] : (gid < 2048) ? bk[gid - 1024] : bv[gid - 2048];
    bqkv[gid] = v;
  }
}

// ---------------- 256x256 8-phase pipelined bf16 NT GEMM (K=1024, m201 template) ----------------
// Identical to R11 EXCEPT: all sched_barrier(0) removed (m141 anti-pattern).
// Ordering still guaranteed: memory-clobbered s_waitcnt asms + raw barriers; C++ ds_reads
// are compiler-dependency-tracked into the MFMAs. R11 ref-checked this ledger (absmax ok).
template<bool OUT_BF16>
__global__ __launch_bounds__(512) void gemm8p(const unsigned short* __restrict__ A,
                                              const unsigned short* __restrict__ Bm,
                                              const float* __restrict__ bias,
                                              void* __restrict__ Cout,
                                              int N) {
  constexpr int K = 1024;
  __shared__ unsigned short lds[65536];   // 128 KB: [2 dbuf][Ah0|Ah1|Bh0|Bh1][128][64]

  const int tid = threadIdx.x, wid = tid >> 6, lane = tid & 63;
  const int wm = wid >> 2, wn = wid & 3;

  // bijective XCD swizzle, column-major tile walk
  const int nwg = gridDim.x, cpx = nwg >> 3, bid = blockIdx.x;
  const int swz = (bid & 7) * cpx + (bid >> 3);
  constexpr int NBM = Mm / 256;   // 32
  const int m0 = (swz % NBM) << 8, n0 = (swz / NBM) << 8;

  // staging source: thread t covers row (t>>3) of a 64-row group, chunk t&7;
  // pre-swizzled global chunk = (lane&7)^(lane>>3)
  const int rbase = wid * 8 + (lane >> 3);
  const int cst = ((lane & 7) ^ (lane >> 3)) * 8;
  const unsigned short* aP0 = A  + (size_t)(m0 + rbase) * K + cst;
  const unsigned short* aP1 = aP0 + (size_t)128 * K;
  const unsigned short* bP0 = Bm + (size_t)(n0 + rbase) * K + cst;
  const unsigned short* bP1 = bP0 + (size_t)128 * K;

  // read bases (elems): A region = wm half; B region = (wn>>1) half, (wn&1) sub
  const int awb = wm * 8192 + (lane & 15) * 64;
  const int bwb = 16384 + (wn >> 1) * 8192 + (wn & 1) * 4096 + (lane & 15) * 64;
  const int chs0 = (((lane >> 4)) ^ (lane & 7)) * 8;
  const int chs1 = ((4 + (lane >> 4)) ^ (lane & 7)) * 8;

  f32x4 acc[8][4] = {};
  bf16x8s breg[4][2], areg[2][2];

#define GL(sp, off) __builtin_amdgcn_global_load_lds((AS1 const void*)(sp), (AS3 void*)(&lds[off]), 16, 0, 0)
#define STGA(d,h,kt) do { const unsigned short* _s = ((h) ? aP1 : aP0) + (size_t)(kt) * 64; \
    GL(_s,                   (d)*32768 + (h)*8192 +        wid*512); \
    GL(_s + (size_t)64 * K,  (d)*32768 + (h)*8192 + 4096 + wid*512); } while (0)
#define STGB(d,h,kt) do { const unsigned short* _s = ((h) ? bP1 : bP0) + (size_t)(kt) * 64; \
    GL(_s,                   (d)*32768 + 16384 + (h)*8192 +        wid*512); \
    GL(_s + (size_t)64 * K,  (d)*32768 + 16384 + (h)*8192 + 4096 + wid*512); } while (0)
#define LDB(d) do { _Pragma("unroll") for (int fn = 0; fn < 4; ++fn) { \
    breg[fn][0] = *(const bf16x8s*)(&lds[(d)*32768 + bwb + fn*1024 + chs0]); \
    breg[fn][1] = *(const bf16x8s*)(&lds[(d)*32768 + bwb + fn*1024 + chs1]); } } while (0)
#define LDA(d,q) do { _Pragma("unroll") for (int u = 0; u < 2; ++u) { \
    areg[u][0] = *(const bf16x8s*)(&lds[(d)*32768 + awb + ((q)*2+u)*1024 + chs0]); \
    areg[u][1] = *(const bf16x8s*)(&lds[(d)*32768 + awb + ((q)*2+u)*1024 + chs1]); } } while (0)
#define MF16(q) do { _Pragma("unroll") for (int u = 0; u < 2; ++u) _Pragma("unroll") for (int fn = 0; fn < 4; ++fn) { \
    acc[(q)*2+u][fn] = __builtin_amdgcn_mfma_f32_16x16x32_bf16(areg[u][0], breg[fn][0], acc[(q)*2+u][fn], 0, 0, 0); \
    acc[(q)*2+u][fn] = __builtin_amdgcn_mfma_f32_16x16x32_bf16(areg[u][1], breg[fn][1], acc[(q)*2+u][fn], 0, 0, 0); } } while (0)
#define BAR __builtin_amdgcn_s_barrier()
#define LGKM0 asm volatile("s_waitcnt lgkmcnt(0)" ::: "memory")
#define PRIO1 __builtin_amdgcn_s_setprio(1)
#define PRIO0 __builtin_amdgcn_s_setprio(0)

  // prologue: stage tile 0 -> dbuf0 (first 8 loads), tile 1 -> dbuf1
  STGA(0,0,0); STGA(0,1,0); STGB(0,0,0); STGB(0,1,0);
  STGA(1,0,1); STGA(1,1,1); STGB(1,0,1); STGB(1,1,1);
  asm volatile("s_waitcnt vmcnt(8)" ::: "memory");   // tile 0 landed
  BAR;

#pragma unroll 1
  for (int j = 0; j < 8; ++j) {
    const int tA1 = 2*j + 1;          // <=15 always
    const int t0  = (2*j + 2) & 15;
    const int tB1 = (2*j + 3) & 15;
    // ---- K-tile 2j (dbuf0) ----
    LDB(0); LDA(0,0); STGA(1,0,tA1);          BAR; LGKM0;            // P1
    PRIO1; MF16(0); PRIO0; BAR;
    LDA(0,1); STGA(1,1,tA1); STGB(0,0,t0);    BAR; LGKM0;            // P2
    PRIO1; MF16(1); PRIO0; BAR;
    LDA(0,2); STGB(0,1,t0);                   BAR; LGKM0;            // P3
    PRIO1; MF16(2); PRIO0; BAR;
    LDA(0,3);                                 BAR; LGKM0;            // P4
    PRIO1; MF16(3); PRIO0;
    asm volatile("s_waitcnt vmcnt(4)" ::: "memory"); BAR;            // d1 complete
    // ---- K-tile 2j+1 (dbuf1) ----
    LDB(1); LDA(1,0); STGA(0,0,t0);           BAR; LGKM0;            // P5
    PRIO1; MF16(0); PRIO0; BAR;
    LDA(1,1); STGA(0,1,t0); STGB(1,0,tB1);    BAR; LGKM0;            // P6
    PRIO1; MF16(1); PRIO0; BAR;
    LDA(1,2); STGB(1,1,tB1);                  BAR; LGKM0;            // P7
    PRIO1; MF16(2); PRIO0; BAR;
    LDA(1,3);                                 BAR; LGKM0;            // P8
    PRIO1; MF16(3); PRIO0;
    asm volatile("s_waitcnt vmcnt(4)" ::: "memory"); BAR;            // d0 complete
  }
#undef GL
#undef STGA
#undef STGB
#undef LDB
#undef LDA
#undef MF16

  // epilogue: C/D layout col=lane&15, row=(lane>>4)*4+r
  const int r0 = m0 + wm * 128 + (lane >> 4) * 4;
  const int c0 = n0 + wn * 64 + (lane & 15);
#pragma unroll
  for (int fm = 0; fm < 8; ++fm) {
#pragma unroll
    for (int fn = 0; fn < 4; ++fn) {
      const int col = c0 + fn * 16;
      const float bv = bias[col];
#pragma unroll
      for (int r = 0; r < 4; ++r) {
        const int row = r0 + fm * 16 + r;
        const float v = acc[fm][fn][r] + bv;
        if (OUT_BF16)
          ((unsigned short*)Cout)[(size_t)row * N + col] = f2bf(v);
        else
          ((float*)Cout)[(size_t)row * N + col] = v;
      }
    }
  }
}

// ---------------- 128x256 flight-2 GEMM (R7-proven) — output projection ----------------
template<bool OUT_BF16>
__global__ __launch_bounds__(512) void gemm_p3(const unsigned short* __restrict__ A,
                                               const unsigned short* __restrict__ Bm,
                                               const float* __restrict__ bias,
                                               void* __restrict__ Cout,
                                               int N) {
  constexpr int K = 1024, NT = 16;
  __shared__ unsigned short lds[3][24576];   // 144 KB

  const int tid = threadIdx.x, wid = tid >> 6, lane = tid & 63;
  const int wm = wid >> 2, wn = wid & 3;

  const int nwg = gridDim.x, cpx = nwg >> 3, bid = blockIdx.x;
  const int swz = (bid & 7) * cpx + (bid >> 3);
  constexpr int NBM = Mm / 128;   // 64
  const int m0 = (swz % NBM) << 7, n0 = (swz / NBM) << 8;

  const int rbase = wid * 8 + (lane >> 3);
  const int cst = ((lane & 7) ^ (lane >> 3)) * 8;
  const unsigned short* aS0 = A + (size_t)(m0 + rbase) * K + cst;
  const unsigned short* aS1 = A + (size_t)(m0 + 64 + rbase) * K + cst;
  const unsigned short* bS0 = Bm + (size_t)(n0 + rbase) * K + cst;
  const unsigned short* bS1 = Bm + (size_t)(n0 + 64 + rbase) * K + cst;
  const unsigned short* bS2 = Bm + (size_t)(n0 + 128 + rbase) * K + cst;
  const unsigned short* bS3 = Bm + (size_t)(n0 + 192 + rbase) * K + cst;
  const int dA0 = wid * 512, dA1 = 4096 + wid * 512;
  const int dB0 = 8192 + wid * 512, dB1 = 12288 + wid * 512;
  const int dB2 = 16384 + wid * 512, dB3 = 20480 + wid * 512;

#define STG(bf, kt) do {                                                                   \
    const size_t ko = (size_t)(kt) * 64;                                                   \
    __builtin_amdgcn_global_load_lds((AS1 const void*)(aS0 + ko), (AS3 void*)(&lds[bf][dA0]), 16, 0, 0); \
    __builtin_amdgcn_global_load_lds((AS1 const void*)(aS1 + ko), (AS3 void*)(&lds[bf][dA1]), 16, 0, 0); \
    __builtin_amdgcn_global_load_lds((AS1 const void*)(bS0 + ko), (AS3 void*)(&lds[bf][dB0]), 16, 0, 0); \
    __builtin_amdgcn_global_load_lds((AS1 const void*)(bS1 + ko), (AS3 void*)(&lds[bf][dB1]), 16, 0, 0); \
    __builtin_amdgcn_global_load_lds((AS1 const void*)(bS2 + ko), (AS3 void*)(&lds[bf][dB2]), 16, 0, 0); \
    __builtin_amdgcn_global_load_lds((AS1 const void*)(bS3 + ko), (AS3 void*)(&lds[bf][dB3]), 16, 0, 0); \
  } while (0)

  int aoff[2][4], boff[2][4];
#pragma unroll
  for (int kk = 0; kk < 2; ++kk) {
    const int chs = ((kk * 4 + (lane >> 4)) ^ (lane & 7)) * 8;
#pragma unroll
    for (int f = 0; f < 4; ++f) {
      aoff[kk][f] = (wm * 64 + f * 16 + (lane & 15)) * 64 + chs;
      boff[kk][f] = 8192 + (wn * 64 + f * 16 + (lane & 15)) * 64 + chs;
    }
  }

  f32x4 acc[4][4] = {};

  STG(0, 0);
  STG(1, 1);
  asm volatile("s_waitcnt vmcnt(6)" ::: "memory");
  __builtin_amdgcn_sched_barrier(0);
  __builtin_amdgcn_s_barrier();
  __builtin_amdgcn_sched_barrier(0);

  int cur = 0, stg = 2;
  for (int t = 0; t < NT; ++t) {
    if (t + 2 < NT) STG(stg, t + 2);

    const unsigned short* L = &lds[cur][0];
    bf16x8s a[2][4], b[2][4];
#pragma unroll
    for (int kk = 0; kk < 2; ++kk) {
#pragma unroll
      for (int f = 0; f < 4; ++f) {
        a[kk][f] = *(const bf16x8s*)(L + aoff[kk][f]);
        b[kk][f] = *(const bf16x8s*)(L + boff[kk][f]);
      }
    }
    __builtin_amdgcn_s_setprio(1);
#pragma unroll
    for (int kk = 0; kk < 2; ++kk)
#pragma unroll
      for (int fm = 0; fm < 4; ++fm)
#pragma unroll
        for (int fn = 0; fn < 4; ++fn)
          acc[fm][fn] = __builtin_amdgcn_mfma_f32_16x16x32_bf16(a[kk][fm], b[kk][fn], acc[fm][fn], 0, 0, 0);
    __builtin_amdgcn_s_setprio(0);

    if (t + 1 < NT) {
      if (t + 2 < NT) asm volatile("s_waitcnt vmcnt(6)" ::: "memory");
      else            asm volatile("s_waitcnt vmcnt(0)" ::: "memory");
      __builtin_amdgcn_sched_barrier(0);
      __builtin_amdgcn_s_barrier();
      __builtin_amdgcn_sched_barrier(0);
    }
    cur = (cur == 2) ? 0 : cur + 1;
    stg = (stg == 2) ? 0 : stg + 1;
  }
#undef STG

  const int r0 = m0 + wm * 64 + (lane >> 4) * 4;
  const int c0 = n0 + wn * 64 + (lane & 15);
#pragma unroll
  for (int fm = 0; fm < 4; ++fm) {
#pragma unroll
    for (int fn = 0; fn < 4; ++fn) {
      const int col = c0 + fn * 16;
      const float bv = bias[col];
#pragma unroll
      for (int r = 0; r < 4; ++r) {
        const int row = r0 + fm * 16 + r;
        const float v = acc[fm][fn][r] + bv;
        if (OUT_BF16)
          ((unsigned short*)Cout)[(size_t)row * N + col] = f2bf(v);
        else
          ((float*)Cout)[(size_t)row * N + col] = v;
      }
    }
  }
}

// ---------------- banded local attention: 2 threads per (b,h,n) row ----------------
#define TN 128
#define KVROWS (TN + 2 * W2)   // 148 staged rows

__global__ void attn_kernel(const unsigned short* __restrict__ QKV, // [Mm][3072]
                            unsigned short* __restrict__ AO,        // [Mm][1024]
                            float* __restrict__ attn_last) {        // [Bb*Hh*11]
  __shared__ uint4 Kl[KVROWS * 8];
  __shared__ uint4 Vl[KVROWS * 8];

  const int nt = Nn / TN;            // 32
  const int bid = blockIdx.x;
  const int tile = bid & (nt - 1);
  const int bh = bid / nt;
  const int h = bh & (Hh - 1), b = bh / Hh;
  const int n0 = tile * TN;
  const int tid = threadIdx.x;

  for (int idx = tid; idx < KVROWS * 8; idx += 256) {
    const int r = idx >> 3, c = idx & 7;
    const int pos = n0 - W2 + r;
    uint4 kv = make_uint4(0, 0, 0, 0), vv = make_uint4(0, 0, 0, 0);
    if (pos >= 0 && pos < Nn) {
      const uint4* row = (const uint4*)(QKV + (size_t)(b * Nn + pos) * 3072);
      kv = row[128 + h * 8 + c];
      vv = row[256 + h * 8 + c];
    }
    const int slot = c ^ (r & 7);
    Kl[r * 8 + slot] = kv;
    Vl[r * 8 + slot] = vv;
  }
  __syncthreads();

  const int row  = tid >> 1;
  const int half = tid & 1;
  const int n = n0 + row;
  const size_t m = (size_t)b * Nn + n;

  const uint4* qrow = (const uint4*)(QKV + m * 3072) + h * 8 + half * 4;
  const uint4 qd0 = qrow[0], qd1 = qrow[1], qd2 = qrow[2], qd3 = qrow[3];

  float p[WINSZ];
#pragma unroll
  for (int w = 0; w < WINSZ; ++w) p[w] = 0.f;

#pragma unroll
  for (int c = 0; c < 4; ++c) {
    const uint4 qv = (c == 0) ? qd0 : (c == 1) ? qd1 : (c == 2) ? qd2 : qd3;
    const float q0 = bflo(qv.x), q1 = bfhi(qv.x);
    const float q2 = bflo(qv.y), q3 = bfhi(qv.y);
    const float q4 = bflo(qv.z), q5 = bfhi(qv.z);
    const float q6 = bflo(qv.w), q7 = bfhi(qv.w);
#pragma unroll 7
    for (int w = 0; w < WINSZ; ++w) {
      const int r = row + w;
      const uint4 v = Kl[r * 8 + ((half * 4 + c) ^ (r & 7))];
      float a0 = q0 * bflo(v.x);
      float a1 = q1 * bfhi(v.x);
      a0 += q2 * bflo(v.y);
      a1 += q3 * bfhi(v.y);
      a0 += q4 * bflo(v.z);
      a1 += q5 * bfhi(v.z);
      a0 += q6 * bflo(v.w);
      a1 += q7 * bfhi(v.w);
      p[w] += a0 + a1;
    }
  }

#pragma unroll
  for (int w = 0; w < WINSZ; ++w) {
    float t = p[w];
    t += __shfl_xor(t, 1, 64);
    const int pos = n - W2 + w;
    p[w] = (pos < 0 || pos >= Nn) ? -1e30f : t * 0.125f;
  }
  float mx = p[0];
#pragma unroll
  for (int w = 1; w < WINSZ; ++w) mx = fmaxf(mx, p[w]);
  float sum = 0.f;
#pragma unroll
  for (int w = 0; w < WINSZ; ++w) { p[w] = __expf(p[w] - mx); sum += p[w]; }
  const float inv = 1.0f / sum;

  if (n == Nn - 1 && half == 0) {
#pragma unroll
    for (int w = 0; w <= W2; ++w)
      attn_last[(b * Hh + h) * (W2 + 1) + w] = p[w] * inv;
  }

  uint4* orow = (uint4*)(AO + m * Cc + h * Dd) + half * 4;
#pragma unroll
  for (int c = 0; c < 4; ++c) {
    float o0 = 0.f, o1 = 0.f, o2 = 0.f, o3 = 0.f;
    float o4 = 0.f, o5 = 0.f, o6 = 0.f, o7 = 0.f;
#pragma unroll 7
    for (int w = 0; w < WINSZ; ++w) {
      const int r = row + w;
      const uint4 v = Vl[r * 8 + ((half * 4 + c) ^ (r & 7))];
      const float pw = p[w];
      o0 += pw * bflo(v.x);
      o1 += pw * bfhi(v.x);
      o2 += pw * bflo(v.y);
      o3 += pw * bfhi(v.y);
      o4 += pw * bflo(v.z);
      o5 += pw * bfhi(v.z);
      o6 += pw * bflo(v.w);
      o7 += pw * bfhi(v.w);
    }
    unsigned int d0 = (unsigned int)f2bf(o0 * inv) | ((unsigned int)f2bf(o1 * inv) << 16);
    unsigned int d1 = (unsigned int)f2bf(o2 * inv) | ((unsigned int)f2bf(o3 * inv) << 16);
    unsigned int d2 = (unsigned int)f2bf(o4 * inv) | ((unsigned int)f2bf(o5 * inv) << 16);
    unsigned int d3 = (unsigned int)f2bf(o6 * inv) | ((unsigned int)f2bf(o7 * inv) << 16);
    orow[c] = make_uint4(d0, d1, d2, d3);
  }
}

// ---------------- launch ----------------
extern "C" void kernel_launch(void* const* d_in, const int* in_sizes, int n_in,
                              void* d_out, int out_size, void* d_ws, size_t ws_size,
                              hipStream_t stream) {
  const float* q    = (const float*)d_in[0];
  const float* Wq_w = (const float*)d_in[1];
  const float* Wq_b = (const float*)d_in[2];
  const float* Wk_w = (const float*)d_in[3];
  const float* Wk_b = (const float*)d_in[4];
  const float* Wv_w = (const float*)d_in[5];
  const float* Wv_b = (const float*)d_in[6];
  const float* Wo_w = (const float*)d_in[7];
  const float* Wo_b = (const float*)d_in[8];
  float* out = (float*)d_out;                       // [Mm*Cc] + [Bb*Hh*11]
  float* attn_last = out + (size_t)Mm * Cc;

  // workspace carve (bytes)
  char* ws = (char*)d_ws;
  unsigned short* qb   = (unsigned short*)(ws);                       // 16 MB
  unsigned short* Wqkv = (unsigned short*)(ws + 16777216);            // 6 MB
  unsigned short* Wo16 = (unsigned short*)(ws + 16777216 + 6291456);  // 2 MB
  float*          bqkv = (float*)(ws + 25165824);                     // 3072 f32
  unsigned short* QKV  = (unsigned short*)(ws + 25182208);            // 48 MB
  unsigned short* AO   = (unsigned short*)(ws + 75513856);            // 16 MB

  // 1) fused converts (q, Wq, Wk, Wv, Wo) + bias gather — one launch
  cvt_all<<<2048, 256, 0, stream>>>((const float4*)q,
                                    (const float4*)Wq_w, (const float4*)Wk_w,
                                    (const float4*)Wv_w, (const float4*)Wo_w,
                                    Wq_b, Wk_b, Wv_b,
                                    (us4*)qb, (us4*)Wqkv, (us4*)Wo16, bqkv);

  // 2) fused QKV projection: [8192,1024] x [3072,1024]^T -> bf16 [8192,3072]
  {
    dim3 grid((Mm / 256) * (3072 / 256));   // 384, %8==0
    gemm8p<true><<<grid, 512, 0, stream>>>(qb, Wqkv, bqkv, (void*)QKV, 3072);
  }

  // 3) windowed attention -> bf16 [8192,1024] + attn_last tail of d_out
  {
    dim3 grid(Bb * Hh * (Nn / TN));
    attn_kernel<<<grid, 256, 0, stream>>>(QKV, AO, attn_last);
  }

  // 4) output projection: [8192,1024] x [1024,1024]^T -> fp32 d_out
  {
    dim3 grid((Mm / 128) * (Cc / 256));     // 256, %8==0
    gemm_p3<false><<<grid, 512, 0, stream>>>(AO, Wo16, Wo_b, (void*)out, Cc);
  }
}